// Round 1
// baseline (317.702 us; speedup 1.0000x reference)
//
#include <hip/hip_runtime.h>
#include <hip/hip_bf16.h>

// Problem constants: B=8, S=1024, D=1024, H=16, HD=64, R=8, SCALING=2.0,
// DFF=4096, DC=512, NC=3. Output depends only on h[:,0] -> slice everything
// after K/V to 8 rows.

typedef __bf16 bf16x8 __attribute__((ext_vector_type(8)));
typedef float f32x4 __attribute__((ext_vector_type(4)));

__device__ __forceinline__ float bf2f(unsigned short u) {
  union { unsigned int i; float f; } v; v.i = ((unsigned int)u) << 16; return v.f;
}
__device__ __forceinline__ unsigned short f2bf(float f) {
  union { float f; unsigned int i; } v; v.f = f;
  unsigned int u = v.i;
  u += 0x7FFFu + ((u >> 16) & 1u);
  return (unsigned short)(u >> 16);
}
__device__ __forceinline__ float gelu_exact(float x) {
  return 0.5f * x * (1.0f + erff(x * 0.70710678118654752440f));
}

// ---------------- fold LoRA into effective weight: W_eff[n][k] = W[n][k] + 2*sum_r B[n][r]*A[r][k]
__global__ __launch_bounds__(256) void fold_kernel(
    const float* __restrict__ W, const float* __restrict__ A,
    const float* __restrict__ Bm, void* __restrict__ out, int out_bf16) {
  int i = blockIdx.x * 256 + threadIdx.x;      // over D*D = 1M
  int n = i >> 10, k = i & 1023;
  float acc = W[i];
#pragma unroll
  for (int r = 0; r < 8; ++r) acc += 2.0f * Bm[n * 8 + r] * A[r * 1024 + k];
  if (out_bf16) ((unsigned short*)out)[i] = f2bf(acc);
  else          ((float*)out)[i] = acc;
}

// ---------------- LayerNorm over D=1024, one block per row
__global__ __launch_bounds__(256) void ln_kernel(
    const float* __restrict__ x, const float* __restrict__ g,
    const float* __restrict__ b, void* __restrict__ out, int out_bf16) {
  size_t row = blockIdx.x;
  const float* xr = x + row * 1024;
  int t = threadIdx.x;
  float4 v = ((const float4*)xr)[t];
  float s  = v.x + v.y + v.z + v.w;
  float sq = v.x * v.x + v.y * v.y + v.z * v.z + v.w * v.w;
#pragma unroll
  for (int o = 32; o; o >>= 1) { s += __shfl_down(s, o); sq += __shfl_down(sq, o); }
  __shared__ float rs_[4], rq_[4], stat[2];
  int w = t >> 6, l = t & 63;
  if (l == 0) { rs_[w] = s; rq_[w] = sq; }
  __syncthreads();
  if (t == 0) {
    float S = rs_[0] + rs_[1] + rs_[2] + rs_[3];
    float Q = rq_[0] + rq_[1] + rq_[2] + rq_[3];
    float mu = S * (1.0f / 1024.0f);
    float var = Q * (1.0f / 1024.0f) - mu * mu;
    stat[0] = mu; stat[1] = rsqrtf(var + 1e-5f);
  }
  __syncthreads();
  float mu = stat[0], rstd = stat[1];
  float4 gg = ((const float4*)g)[t];
  float4 bb = ((const float4*)b)[t];
  float o0 = (v.x - mu) * rstd * gg.x + bb.x;
  float o1 = (v.y - mu) * rstd * gg.y + bb.y;
  float o2 = (v.z - mu) * rstd * gg.z + bb.z;
  float o3 = (v.w - mu) * rstd * gg.w + bb.w;
  if (out_bf16) {
    unsigned short* op = (unsigned short*)out + row * 1024 + t * 4;
    op[0] = f2bf(o0); op[1] = f2bf(o1); op[2] = f2bf(o2); op[3] = f2bf(o3);
  } else {
    float* op = (float*)out + row * 1024 + t * 4;
    op[0] = o0; op[1] = o1; op[2] = o2; op[3] = o3;
  }
}

// ---------------- big GEMM: C[8192][1024] = A[8192][1024](bf16) * W[1024][1024]^T(bf16), fp32 out
// m97 structure: 128x128 tile, BK=32, 4 waves (2x2 of 64x64), global_load_lds w=16.
__device__ __forceinline__ void gload_lds16(const void* g, void* l) {
  __builtin_amdgcn_global_load_lds(
      (__attribute__((address_space(1))) void*)(g),
      (__attribute__((address_space(3))) void*)(l), 16, 0, 0);
}

__global__ __launch_bounds__(256, 2) void gemm_kv(
    const unsigned short* __restrict__ h,
    const unsigned short* __restrict__ Wk, const unsigned short* __restrict__ Wv,
    float* __restrict__ Kout, float* __restrict__ Vout) {
  __shared__ unsigned short sA[128 * 32];
  __shared__ unsigned short sB[128 * 32];
  // bijective XCD swizzle, nwg=1024 (divisible by 8)
  int wg = blockIdx.x;
  int swz = (wg & 7) * 128 + (wg >> 3);
  int proj = swz >> 9;               // 512 blocks per projection
  int rem = swz & 511;
  int nb = rem & 7, mb = rem >> 3;   // 8 col-blocks x 64 row-blocks
  const unsigned short* W = proj ? Wv : Wk;
  float* C = proj ? Vout : Kout;
  int brow = mb << 7, bcol = nb << 7;
  int t = threadIdx.x;
  int w = t >> 6, l = t & 63;
  int wr = (w >> 1) << 6, wc = (w & 1) << 6;  // wave's 64x64 quadrant
  int frow = l & 15, fk = (l >> 4) << 3;      // MFMA fragment addressing
  f32x4 acc[4][4];
#pragma unroll
  for (int m = 0; m < 4; ++m)
#pragma unroll
    for (int n = 0; n < 4; ++n) acc[m][n] = (f32x4){0.f, 0.f, 0.f, 0.f};
  // staging: 8KB per tile = 8 chunks of 1024B; wave w does chunks 2w,2w+1.
  int e0 = (w * 2) * 512 + l * 8;    // element offset in tile
  int e1 = e0 + 512;
  int r0 = e0 >> 5, c0 = e0 & 31;
  int r1 = e1 >> 5, c1 = e1 & 31;
  const unsigned short* gA0 = h + (size_t)(brow + r0) * 1024 + c0;
  const unsigned short* gA1 = h + (size_t)(brow + r1) * 1024 + c1;
  const unsigned short* gB0 = W + (size_t)(bcol + r0) * 1024 + c0;
  const unsigned short* gB1 = W + (size_t)(bcol + r1) * 1024 + c1;
  for (int kt = 0; kt < 1024; kt += 32) {
    gload_lds16(gA0 + kt, &sA[e0]);
    gload_lds16(gA1 + kt, &sA[e1]);
    gload_lds16(gB0 + kt, &sB[e0]);
    gload_lds16(gB1 + kt, &sB[e1]);
    __syncthreads();
    bf16x8 a[4], b[4];
#pragma unroll
    for (int m = 0; m < 4; ++m)
      a[m] = *(const bf16x8*)&sA[(wr + m * 16 + frow) * 32 + fk];
#pragma unroll
    for (int n = 0; n < 4; ++n)
      b[n] = *(const bf16x8*)&sB[(wc + n * 16 + frow) * 32 + fk];
#pragma unroll
    for (int m = 0; m < 4; ++m)
#pragma unroll
      for (int n = 0; n < 4; ++n)
        acc[m][n] = __builtin_amdgcn_mfma_f32_16x16x32_bf16(a[m], b[n], acc[m][n], 0, 0, 0);
    __syncthreads();
  }
  // C/D layout: col = lane&15, row = (lane>>4)*4 + reg
  int crow = (l >> 4) << 2, ccol = l & 15;
#pragma unroll
  for (int m = 0; m < 4; ++m) {
    int gr = brow + wr + m * 16 + crow;
#pragma unroll
    for (int n = 0; n < 4; ++n) {
      int gc = bcol + wc + n * 16 + ccol;
#pragma unroll
      for (int j = 0; j < 4; ++j)
        C[(size_t)(gr + j) * 1024 + gc] = acc[m][n][j];
    }
  }
}

// ---------------- small GEMM: Y[8][N] = op(X[8][K] @ W[N][K]^T + bias) (+resid)
// 16 cols x 16 K-slices per 256-thread block.
__global__ __launch_bounds__(256) void small_gemm(
    const void* __restrict__ X, int xbf, long xs,
    const float* __restrict__ W, const float* __restrict__ bias,
    const float* __restrict__ resid, long rstride,
    float* __restrict__ Y, int N, int K, int do_gelu) {
  int t = threadIdx.x;
  int cl = t >> 4;
  int s = t & 15;
  int col = blockIdx.x * 16 + cl;
  int klen = K >> 4;
  int k0 = s * klen;
  const float* Wr = W + (size_t)col * K + k0;
  float acc[8];
#pragma unroll
  for (int m = 0; m < 8; ++m) acc[m] = 0.f;
  for (int kk = 0; kk < klen; kk += 4) {
    float4 w4 = *(const float4*)(Wr + kk);
#pragma unroll
    for (int m = 0; m < 8; ++m) {
      size_t base = (size_t)m * xs + k0 + kk;
      float x0, x1, x2, x3;
      if (xbf) {
        const unsigned short* xp = (const unsigned short*)X + base;
        x0 = bf2f(xp[0]); x1 = bf2f(xp[1]); x2 = bf2f(xp[2]); x3 = bf2f(xp[3]);
      } else {
        const float* xp = (const float*)X + base;
        x0 = xp[0]; x1 = xp[1]; x2 = xp[2]; x3 = xp[3];
      }
      acc[m] += w4.x * x0 + w4.y * x1 + w4.z * x2 + w4.w * x3;
    }
  }
  __shared__ float part[256][8];
#pragma unroll
  for (int m = 0; m < 8; ++m) part[t][m] = acc[m];
  __syncthreads();
  if (t < 128) {
    int c2 = t >> 3, m = t & 7;
    float v = 0.f;
#pragma unroll
    for (int ss = 0; ss < 16; ++ss) v += part[c2 * 16 + ss][m];
    int gcol = blockIdx.x * 16 + c2;
    if (bias)  v += bias[gcol];
    if (do_gelu) v = gelu_exact(v);
    if (resid) v += resid[(size_t)m * rstride + gcol];
    Y[(size_t)m * N + gcol] = v;
  }
}

// ---------------- attention at query position 0: one block per (b,h)
__global__ __launch_bounds__(256) void attn0_kernel(
    const float* __restrict__ q0, const float* __restrict__ K,
    const float* __restrict__ V, float* __restrict__ ctx) {
  int bh = blockIdx.x;
  int b = bh >> 4, hh = bh & 15;
  int t = threadIdx.x;
  __shared__ float sq[64];
  __shared__ float sp[1024];
  __shared__ float rbuf[8];
  __shared__ float sstat[2];
  __shared__ float part[4][64];
  if (t < 64) sq[t] = q0[b * 1024 + hh * 64 + t];
  __syncthreads();
  const float* Kb = K + (size_t)b * 1024 * 1024 + hh * 64;
  float sc[4], lmax = -1e30f;
#pragma unroll
  for (int i = 0; i < 4; ++i) {
    int k = t + i * 256;
    const float* Kr = Kb + (size_t)k * 1024;
    float s = 0.f;
#pragma unroll
    for (int d = 0; d < 64; d += 4) {
      float4 kv = *(const float4*)(Kr + d);
      s += sq[d] * kv.x + sq[d + 1] * kv.y + sq[d + 2] * kv.z + sq[d + 3] * kv.w;
    }
    sc[i] = s * 0.125f;   // 1/sqrt(64)
    lmax = fmaxf(lmax, sc[i]);
  }
#pragma unroll
  for (int o = 32; o; o >>= 1) lmax = fmaxf(lmax, __shfl_down(lmax, o));
  int w = t >> 6, l = t & 63;
  if (l == 0) rbuf[w] = lmax;
  __syncthreads();
  if (t == 0) sstat[0] = fmaxf(fmaxf(rbuf[0], rbuf[1]), fmaxf(rbuf[2], rbuf[3]));
  __syncthreads();
  float gmax = sstat[0];
  float lsum = 0.f;
#pragma unroll
  for (int i = 0; i < 4; ++i) {
    float e = expf(sc[i] - gmax);
    sp[t + i * 256] = e;
    lsum += e;
  }
#pragma unroll
  for (int o = 32; o; o >>= 1) lsum += __shfl_down(lsum, o);
  if (l == 0) rbuf[4 + w] = lsum;
  __syncthreads();
  if (t == 0) sstat[1] = 1.0f / (rbuf[4] + rbuf[5] + rbuf[6] + rbuf[7]);
  __syncthreads();
  float inv = sstat[1];
  int d = t & 63, kq = t >> 6;
  const float* Vb = V + ((size_t)b * 1024 + kq * 256) * 1024 + hh * 64 + d;
  float a = 0.f;
  for (int k = 0; k < 256; ++k) a += sp[kq * 256 + k] * Vb[(size_t)k * 1024];
  part[kq][d] = a;
  __syncthreads();
  if (t < 64)
    ctx[b * 1024 + hh * 64 + t] =
        (part[0][t] + part[1][t] + part[2][t] + part[3][t]) * inv;
}

// ---------------- classifier head: out[b][n] = cmid[b] . Wc2[n] + bc2[n], 24 outputs
__global__ __launch_bounds__(256) void logits_kernel(
    const float* __restrict__ cmid, const float* __restrict__ Wc2,
    const float* __restrict__ bc2, float* __restrict__ out) {
  int t = threadIdx.x;
  int o = t >> 3, s = t & 7;
  float a = 0.f;
  if (o < 24) {
    int b = o / 3, n = o % 3;
    const float* x = cmid + b * 512 + s * 64;
    const float* w = Wc2 + n * 512 + s * 64;
#pragma unroll
    for (int k = 0; k < 64; ++k) a += x[k] * w[k];
  }
  __shared__ float part[32][8];
  part[o][s] = a;
  __syncthreads();
  if (t < 24) {
    float v = bc2[t % 3];
#pragma unroll
    for (int ss = 0; ss < 8; ++ss) v += part[t][ss];
    out[t] = v;
  }
}

extern "C" void kernel_launch(void* const* d_in, const int* in_sizes, int n_in,
                              void* d_out, int out_size, void* d_ws, size_t ws_size,
                              hipStream_t stream) {
  const float* x    = (const float*)d_in[0];
  const float* Wq   = (const float*)d_in[1];
  const float* Aq   = (const float*)d_in[2];
  const float* Bq   = (const float*)d_in[3];
  const float* Wk   = (const float*)d_in[4];
  const float* Ak   = (const float*)d_in[5];
  const float* Bk   = (const float*)d_in[6];
  const float* Wv   = (const float*)d_in[7];
  const float* Av   = (const float*)d_in[8];
  const float* Bv   = (const float*)d_in[9];
  const float* Wo   = (const float*)d_in[10];
  const float* Ao   = (const float*)d_in[11];
  const float* Bo   = (const float*)d_in[12];
  const float* ln1g = (const float*)d_in[13];
  const float* ln1b = (const float*)d_in[14];
  const float* ln2g = (const float*)d_in[15];
  const float* ln2b = (const float*)d_in[16];
  const float* W1   = (const float*)d_in[17];
  const float* b1   = (const float*)d_in[18];
  const float* W2   = (const float*)d_in[19];
  const float* b2   = (const float*)d_in[20];
  const float* Wc1  = (const float*)d_in[21];
  const float* bc1  = (const float*)d_in[22];
  const float* Wc2  = (const float*)d_in[23];
  const float* bc2  = (const float*)d_in[24];

  char* ws = (char*)d_ws;
  size_t off = 0;
  auto alloc = [&](size_t bytes) {
    void* p = ws + off;
    off += (bytes + 255) & ~(size_t)255;
    return p;
  };
  unsigned short* h_bf = (unsigned short*)alloc((size_t)8192 * 1024 * 2);
  unsigned short* WkE  = (unsigned short*)alloc((size_t)1024 * 1024 * 2);
  unsigned short* WvE  = (unsigned short*)alloc((size_t)1024 * 1024 * 2);
  float* WqE  = (float*)alloc((size_t)1024 * 1024 * 4);
  float* WoE  = (float*)alloc((size_t)1024 * 1024 * 4);
  float* Kb   = (float*)alloc((size_t)8192 * 1024 * 4);
  float* Vb   = (float*)alloc((size_t)8192 * 1024 * 4);
  float* q0   = (float*)alloc(8 * 1024 * 4);
  float* ctx0 = (float*)alloc(8 * 1024 * 4);
  float* h2   = (float*)alloc(8 * 1024 * 4);
  float* hn   = (float*)alloc(8 * 1024 * 4);
  float* mid  = (float*)alloc(8 * 4096 * 4);
  float* pooled = (float*)alloc(8 * 1024 * 4);
  float* cmid = (float*)alloc(8 * 512 * 4);

  // fold LoRA into effective weights (K/V -> bf16 for MFMA, Q/O -> fp32)
  fold_kernel<<<4096, 256, 0, stream>>>(Wk, Ak, Bk, WkE, 1);
  fold_kernel<<<4096, 256, 0, stream>>>(Wv, Av, Bv, WvE, 1);
  fold_kernel<<<4096, 256, 0, stream>>>(Wq, Aq, Bq, WqE, 0);
  fold_kernel<<<4096, 256, 0, stream>>>(Wo, Ao, Bo, WoE, 0);
  // LN1 over all 8192 rows -> bf16 h
  ln_kernel<<<8192, 256, 0, stream>>>(x, ln1g, ln1b, h_bf, 1);
  // K and V projections (the only full-size GEMMs), fused in one launch
  gemm_kv<<<1024, 256, 0, stream>>>(h_bf, WkE, WvE, Kb, Vb);
  // Q projection only for s=0 rows (8 rows; h row b is at b*S*D)
  small_gemm<<<64, 256, 0, stream>>>(h_bf, 1, (long)1048576, WqE, nullptr,
                                     nullptr, 0, q0, 1024, 1024, 0);
  // attention at query position 0
  attn0_kernel<<<128, 256, 0, stream>>>(q0, Kb, Vb, ctx0);
  // O projection + residual (hidden_states[:,0,:])
  small_gemm<<<64, 256, 0, stream>>>(ctx0, 0, 1024, WoE, nullptr,
                                     x, (long)1048576, h2, 1024, 1024, 0);
  // LN2 on 8 rows
  ln_kernel<<<8, 256, 0, stream>>>(h2, ln2g, ln2b, hn, 0);
  // FFN
  small_gemm<<<256, 256, 0, stream>>>(hn, 0, 1024, W1, b1, nullptr, 0,
                                      mid, 4096, 1024, 1);
  small_gemm<<<64, 256, 0, stream>>>(mid, 0, 4096, W2, b2, h2, 1024,
                                     pooled, 1024, 4096, 0);
  // classifier
  small_gemm<<<32, 256, 0, stream>>>(pooled, 0, 1024, Wc1, bc1, nullptr, 0,
                                     cmid, 512, 1024, 1);
  logits_kernel<<<1, 256, 0, stream>>>(cmid, Wc2, bc2, (float*)d_out);
}

// Round 2
// 156.386 us; speedup vs baseline: 2.0315x; 2.0315x over previous
//
#include <hip/hip_runtime.h>
#include <hip/hip_bf16.h>

// B=8, S=1024, D=1024, H=16, HD=64, R=8, SCALING=2.0, DFF=4096, DC=512, NC=3.
// Output depends only on h[:,0] -> everything after K/V is sliced to 8 rows.

typedef __bf16 bf16x8 __attribute__((ext_vector_type(8)));
typedef float f32x4 __attribute__((ext_vector_type(4)));

__device__ __forceinline__ float bf2f(unsigned short u) {
  union { unsigned int i; float f; } v; v.i = ((unsigned int)u) << 16; return v.f;
}
__device__ __forceinline__ unsigned short f2bf(float f) {
  union { float f; unsigned int i; } v; v.f = f;
  unsigned int u = v.i;
  u += 0x7FFFu + ((u >> 16) & 1u);
  return (unsigned short)(u >> 16);
}
__device__ __forceinline__ float gelu_exact(float x) {
  return 0.5f * x * (1.0f + erff(x * 0.70710678118654752440f));
}

// ---------------- fold LoRA: W_eff[n][k] = W[n][k] + 2*sum_r B[n][r]*A[r][k]
__global__ __launch_bounds__(256) void fold_kernel(
    const float* __restrict__ W, const float* __restrict__ A,
    const float* __restrict__ Bm, void* __restrict__ out, int out_bf16) {
  int i = blockIdx.x * 256 + threadIdx.x;      // over D*D = 1M
  int n = i >> 10, k = i & 1023;
  float acc = W[i];
#pragma unroll
  for (int r = 0; r < 8; ++r) acc += 2.0f * Bm[n * 8 + r] * A[r * 1024 + k];
  if (out_bf16) ((unsigned short*)out)[i] = f2bf(acc);
  else          ((float*)out)[i] = acc;
}

// ---------------- LayerNorm over D=1024, one block per row (strided input rows)
__global__ __launch_bounds__(256) void ln_kernel(
    const float* __restrict__ x, long in_stride, const float* __restrict__ g,
    const float* __restrict__ b, void* __restrict__ out, int out_bf16) {
  const float* xr = x + (size_t)blockIdx.x * in_stride;
  int t = threadIdx.x;
  float4 v = ((const float4*)xr)[t];
  float s  = v.x + v.y + v.z + v.w;
  float sq = v.x * v.x + v.y * v.y + v.z * v.z + v.w * v.w;
#pragma unroll
  for (int o = 32; o; o >>= 1) { s += __shfl_down(s, o); sq += __shfl_down(sq, o); }
  __shared__ float rs_[4], rq_[4], stat[2];
  int w = t >> 6, l = t & 63;
  if (l == 0) { rs_[w] = s; rq_[w] = sq; }
  __syncthreads();
  if (t == 0) {
    float S = rs_[0] + rs_[1] + rs_[2] + rs_[3];
    float Q = rq_[0] + rq_[1] + rq_[2] + rq_[3];
    float mu = S * (1.0f / 1024.0f);
    float var = Q * (1.0f / 1024.0f) - mu * mu;
    stat[0] = mu; stat[1] = rsqrtf(var + 1e-5f);
  }
  __syncthreads();
  float mu = stat[0], rstd = stat[1];
  float4 gg = ((const float4*)g)[t];
  float4 bb = ((const float4*)b)[t];
  float o0 = (v.x - mu) * rstd * gg.x + bb.x;
  float o1 = (v.y - mu) * rstd * gg.y + bb.y;
  float o2 = (v.z - mu) * rstd * gg.z + bb.z;
  float o3 = (v.w - mu) * rstd * gg.w + bb.w;
  if (out_bf16) {
    unsigned short* op = (unsigned short*)out + (size_t)blockIdx.x * 1024 + t * 4;
    op[0] = f2bf(o0); op[1] = f2bf(o1); op[2] = f2bf(o2); op[3] = f2bf(o3);
  } else {
    float* op = (float*)out + (size_t)blockIdx.x * 1024 + t * 4;
    op[0] = o0; op[1] = o1; op[2] = o2; op[3] = o3;
  }
}

// ---------------- big GEMM: C[8192][1024](bf16) = A(bf16) * W^T(bf16)
__device__ __forceinline__ void gload_lds16(const void* g, void* l) {
  __builtin_amdgcn_global_load_lds(
      (__attribute__((address_space(1))) void*)(g),
      (__attribute__((address_space(3))) void*)(l), 16, 0, 0);
}

__global__ __launch_bounds__(256, 2) void gemm_kv(
    const unsigned short* __restrict__ h,
    const unsigned short* __restrict__ Wk, const unsigned short* __restrict__ Wv,
    unsigned short* __restrict__ Kout, unsigned short* __restrict__ Vout) {
  __shared__ unsigned short sA[128 * 32];
  __shared__ unsigned short sB[128 * 32];
  int wg = blockIdx.x;
  int swz = (wg & 7) * 128 + (wg >> 3);   // bijective XCD swizzle (nwg=1024)
  int proj = swz >> 9;
  int rem = swz & 511;
  int nb = rem & 7, mb = rem >> 3;
  const unsigned short* W = proj ? Wv : Wk;
  unsigned short* C = proj ? Vout : Kout;
  int brow = mb << 7, bcol = nb << 7;
  int t = threadIdx.x;
  int w = t >> 6, l = t & 63;
  int wr = (w >> 1) << 6, wc = (w & 1) << 6;
  int frow = l & 15, fk = (l >> 4) << 3;
  f32x4 acc[4][4];
#pragma unroll
  for (int m = 0; m < 4; ++m)
#pragma unroll
    for (int n = 0; n < 4; ++n) acc[m][n] = (f32x4){0.f, 0.f, 0.f, 0.f};
  int e0 = (w * 2) * 512 + l * 8;
  int e1 = e0 + 512;
  int r0 = e0 >> 5, c0 = e0 & 31;
  int r1 = e1 >> 5, c1 = e1 & 31;
  const unsigned short* gA0 = h + (size_t)(brow + r0) * 1024 + c0;
  const unsigned short* gA1 = h + (size_t)(brow + r1) * 1024 + c1;
  const unsigned short* gB0 = W + (size_t)(bcol + r0) * 1024 + c0;
  const unsigned short* gB1 = W + (size_t)(bcol + r1) * 1024 + c1;
  for (int kt = 0; kt < 1024; kt += 32) {
    gload_lds16(gA0 + kt, &sA[e0]);
    gload_lds16(gA1 + kt, &sA[e1]);
    gload_lds16(gB0 + kt, &sB[e0]);
    gload_lds16(gB1 + kt, &sB[e1]);
    __syncthreads();
    bf16x8 a[4], b[4];
#pragma unroll
    for (int m = 0; m < 4; ++m)
      a[m] = *(const bf16x8*)&sA[(wr + m * 16 + frow) * 32 + fk];
#pragma unroll
    for (int n = 0; n < 4; ++n)
      b[n] = *(const bf16x8*)&sB[(wc + n * 16 + frow) * 32 + fk];
#pragma unroll
    for (int m = 0; m < 4; ++m)
#pragma unroll
      for (int n = 0; n < 4; ++n)
        acc[m][n] = __builtin_amdgcn_mfma_f32_16x16x32_bf16(a[m], b[n], acc[m][n], 0, 0, 0);
    __syncthreads();
  }
  int crow = (l >> 4) << 2, ccol = l & 15;
#pragma unroll
  for (int m = 0; m < 4; ++m) {
    int gr = brow + wr + m * 16 + crow;
#pragma unroll
    for (int n = 0; n < 4; ++n) {
      int gc = bcol + wc + n * 16 + ccol;
#pragma unroll
      for (int j = 0; j < 4; ++j)
        C[(size_t)(gr + j) * 1024 + gc] = f2bf(acc[m][n][j]);
    }
  }
}

// ---------------- skinny GEMM: Y[8][N] = f(X[8][K] @ W[N][K]^T + bias) (+resid)
// Coalesced W streaming: lane l reads W[col][i*256 + l*4 .. +3] as float4.
// Wave w owns CPW columns; grid = N/(4*CPW) blocks.
template <int CPW>
__global__ __launch_bounds__(256) void skinny_gemm(
    const float* __restrict__ X,                 // [8][K] contiguous
    const float* __restrict__ W,                 // [N][K]
    const float* __restrict__ bias,
    const float* __restrict__ resid, long rstride,
    float* __restrict__ Y, int N, int K, int do_gelu) {
  __shared__ float sX[8][1024];
  int t = threadIdx.x, w = t >> 6, l = t & 63;
  int col0 = blockIdx.x * (4 * CPW) + w * CPW;
  float acc[CPW][8];
#pragma unroll
  for (int c = 0; c < CPW; ++c)
#pragma unroll
    for (int m = 0; m < 8; ++m) acc[c][m] = 0.f;
  for (int kc = 0; kc < K; kc += 1024) {
    // stage X chunk: 8x1024 floats = 2048 float4s
    for (int i = t; i < 2048; i += 256) {
      int m = i >> 8, p = i & 255;
      ((float4*)sX[m])[p] = *(const float4*)(X + (size_t)m * K + kc + p * 4);
    }
    __syncthreads();
#pragma unroll
    for (int i = 0; i < 4; ++i) {
      int k = i * 256 + l * 4;
      float4 xv[8];
#pragma unroll
      for (int m = 0; m < 8; ++m) xv[m] = *(const float4*)&sX[m][k];
#pragma unroll
      for (int c = 0; c < CPW; ++c) {
        float4 wv = *(const float4*)(W + (size_t)(col0 + c) * K + kc + k);
#pragma unroll
        for (int m = 0; m < 8; ++m)
          acc[c][m] += wv.x * xv[m].x + wv.y * xv[m].y + wv.z * xv[m].z + wv.w * xv[m].w;
      }
    }
    __syncthreads();
  }
#pragma unroll
  for (int c = 0; c < CPW; ++c)
#pragma unroll
    for (int m = 0; m < 8; ++m) {
      float v = acc[c][m];
#pragma unroll
      for (int o = 32; o; o >>= 1) v += __shfl_down(v, o);
      acc[c][m] = v;
    }
  if (l == 0) {
#pragma unroll
    for (int c = 0; c < CPW; ++c) {
      int col = col0 + c;
      float bv = bias ? bias[col] : 0.f;
#pragma unroll
      for (int m = 0; m < 8; ++m) {
        float v = acc[c][m] + bv;
        if (do_gelu) v = gelu_exact(v);
        if (resid) v += resid[(size_t)m * rstride + col];
        Y[(size_t)m * N + col] = v;
      }
    }
  }
}

// ---------------- attention at query position 0 (bf16 K/V): one block per (b,h)
__global__ __launch_bounds__(256) void attn0_kernel(
    const float* __restrict__ q0, const unsigned short* __restrict__ K,
    const unsigned short* __restrict__ V, float* __restrict__ ctx) {
  int bh = blockIdx.x;
  int b = bh >> 4, hh = bh & 15;
  int t = threadIdx.x;
  __shared__ float sq[64];
  __shared__ float sp[1024];
  __shared__ float rbuf[8];
  __shared__ float sstat[2];
  __shared__ float part[4][64];
  if (t < 64) sq[t] = q0[b * 1024 + hh * 64 + t];
  __syncthreads();
  const unsigned short* Kb = K + (size_t)b * 1024 * 1024 + hh * 64;
  float sc[4], lmax = -1e30f;
#pragma unroll
  for (int i = 0; i < 4; ++i) {
    int k = t + i * 256;
    const unsigned short* Kr = Kb + (size_t)k * 1024;
    float s = 0.f;
#pragma unroll
    for (int d = 0; d < 64; d += 4) {
      ushort4 kv = *(const ushort4*)(Kr + d);
      s += sq[d] * bf2f(kv.x) + sq[d + 1] * bf2f(kv.y) +
           sq[d + 2] * bf2f(kv.z) + sq[d + 3] * bf2f(kv.w);
    }
    sc[i] = s * 0.125f;
    lmax = fmaxf(lmax, sc[i]);
  }
#pragma unroll
  for (int o = 32; o; o >>= 1) lmax = fmaxf(lmax, __shfl_down(lmax, o));
  int w = t >> 6, l = t & 63;
  if (l == 0) rbuf[w] = lmax;
  __syncthreads();
  if (t == 0) sstat[0] = fmaxf(fmaxf(rbuf[0], rbuf[1]), fmaxf(rbuf[2], rbuf[3]));
  __syncthreads();
  float gmax = sstat[0];
  float lsum = 0.f;
#pragma unroll
  for (int i = 0; i < 4; ++i) {
    float e = expf(sc[i] - gmax);
    sp[t + i * 256] = e;
    lsum += e;
  }
#pragma unroll
  for (int o = 32; o; o >>= 1) lsum += __shfl_down(lsum, o);
  if (l == 0) rbuf[4 + w] = lsum;
  __syncthreads();
  if (t == 0) sstat[1] = 1.0f / (rbuf[4] + rbuf[5] + rbuf[6] + rbuf[7]);
  __syncthreads();
  float inv = sstat[1];
  int d = t & 63, kq = t >> 6;
  const unsigned short* Vb = V + ((size_t)b * 1024 + kq * 256) * 1024 + hh * 64 + d;
  float a = 0.f;
  for (int k = 0; k < 256; ++k) a += sp[kq * 256 + k] * bf2f(Vb[(size_t)k * 1024]);
  part[kq][d] = a;
  __syncthreads();
  if (t < 64)
    ctx[b * 1024 + hh * 64 + t] =
        (part[0][t] + part[1][t] + part[2][t] + part[3][t]) * inv;
}

// ---------------- classifier head: out[b][n] = cmid[b] . Wc2[n] + bc2[n]
__global__ __launch_bounds__(256) void logits_kernel(
    const float* __restrict__ cmid, const float* __restrict__ Wc2,
    const float* __restrict__ bc2, float* __restrict__ out) {
  int t = threadIdx.x;
  int o = t >> 3, s = t & 7;
  float a = 0.f;
  if (o < 24) {
    int b = o / 3, n = o % 3;
    const float* x = cmid + b * 512 + s * 64;
    const float* w = Wc2 + n * 512 + s * 64;
#pragma unroll
    for (int k = 0; k < 64; ++k) a += x[k] * w[k];
  }
  __shared__ float part[32][8];
  part[o][s] = a;
  __syncthreads();
  if (t < 24) {
    float v = bc2[t % 3];
#pragma unroll
    for (int ss = 0; ss < 8; ++ss) v += part[t][ss];
    out[t] = v;
  }
}

extern "C" void kernel_launch(void* const* d_in, const int* in_sizes, int n_in,
                              void* d_out, int out_size, void* d_ws, size_t ws_size,
                              hipStream_t stream) {
  const float* x    = (const float*)d_in[0];
  const float* Wq   = (const float*)d_in[1];
  const float* Aq   = (const float*)d_in[2];
  const float* Bq   = (const float*)d_in[3];
  const float* Wk   = (const float*)d_in[4];
  const float* Ak   = (const float*)d_in[5];
  const float* Bk   = (const float*)d_in[6];
  const float* Wv   = (const float*)d_in[7];
  const float* Av   = (const float*)d_in[8];
  const float* Bv   = (const float*)d_in[9];
  const float* Wo   = (const float*)d_in[10];
  const float* Ao   = (const float*)d_in[11];
  const float* Bo   = (const float*)d_in[12];
  const float* ln1g = (const float*)d_in[13];
  const float* ln1b = (const float*)d_in[14];
  const float* ln2g = (const float*)d_in[15];
  const float* ln2b = (const float*)d_in[16];
  const float* W1   = (const float*)d_in[17];
  const float* b1   = (const float*)d_in[18];
  const float* W2   = (const float*)d_in[19];
  const float* b2   = (const float*)d_in[20];
  const float* Wc1  = (const float*)d_in[21];
  const float* bc1  = (const float*)d_in[22];
  const float* Wc2  = (const float*)d_in[23];
  const float* bc2  = (const float*)d_in[24];

  char* ws = (char*)d_ws;
  size_t off = 0;
  auto alloc = [&](size_t bytes) {
    void* p = ws + off;
    off += (bytes + 255) & ~(size_t)255;
    return p;
  };
  unsigned short* h_bf = (unsigned short*)alloc((size_t)8192 * 1024 * 2);
  unsigned short* WkE  = (unsigned short*)alloc((size_t)1024 * 1024 * 2);
  unsigned short* WvE  = (unsigned short*)alloc((size_t)1024 * 1024 * 2);
  float* WqE  = (float*)alloc((size_t)1024 * 1024 * 4);
  float* WoE  = (float*)alloc((size_t)1024 * 1024 * 4);
  unsigned short* Kb = (unsigned short*)alloc((size_t)8192 * 1024 * 2);
  unsigned short* Vb = (unsigned short*)alloc((size_t)8192 * 1024 * 2);
  float* x0   = (float*)alloc(8 * 1024 * 4);
  float* q0   = (float*)alloc(8 * 1024 * 4);
  float* ctx0 = (float*)alloc(8 * 1024 * 4);
  float* h2   = (float*)alloc(8 * 1024 * 4);
  float* hn   = (float*)alloc(8 * 1024 * 4);
  float* mid  = (float*)alloc(8 * 4096 * 4);
  float* pooled = (float*)alloc(8 * 1024 * 4);
  float* cmid = (float*)alloc(8 * 512 * 4);

  // fold LoRA into effective weights (K/V -> bf16 for MFMA, Q/O -> fp32)
  fold_kernel<<<4096, 256, 0, stream>>>(Wk, Ak, Bk, WkE, 1);
  fold_kernel<<<4096, 256, 0, stream>>>(Wv, Av, Bv, WvE, 1);
  fold_kernel<<<4096, 256, 0, stream>>>(Wq, Aq, Bq, WqE, 0);
  fold_kernel<<<4096, 256, 0, stream>>>(Wo, Ao, Bo, WoE, 0);
  // LN1: full 8192 rows -> bf16; s=0 rows (stride S*D) -> fp32 for Q path
  ln_kernel<<<8192, 256, 0, stream>>>(x, 1024, ln1g, ln1b, h_bf, 1);
  ln_kernel<<<8, 256, 0, stream>>>(x, 1024 * 1024, ln1g, ln1b, x0, 0);
  // K and V projections (the only full-size GEMMs)
  gemm_kv<<<1024, 256, 0, stream>>>(h_bf, WkE, WvE, Kb, Vb);
  // Q projection (8 rows)
  skinny_gemm<1><<<256, 256, 0, stream>>>(x0, WqE, nullptr, nullptr, 0,
                                          q0, 1024, 1024, 0);
  // attention at query position 0
  attn0_kernel<<<128, 256, 0, stream>>>(q0, Kb, Vb, ctx0);
  // O projection + residual (hidden_states[:,0,:])
  skinny_gemm<1><<<256, 256, 0, stream>>>(ctx0, WoE, nullptr, x, 1024 * 1024,
                                          h2, 1024, 1024, 0);
  // LN2 on 8 rows
  ln_kernel<<<8, 256, 0, stream>>>(h2, 1024, ln2g, ln2b, hn, 0);
  // FFN
  skinny_gemm<4><<<256, 256, 0, stream>>>(hn, W1, b1, nullptr, 0,
                                          mid, 4096, 1024, 1);
  skinny_gemm<1><<<256, 256, 0, stream>>>(mid, W2, b2, h2, 1024,
                                          pooled, 1024, 4096, 0);
  // classifier
  skinny_gemm<1><<<128, 256, 0, stream>>>(pooled, Wc1, bc1, nullptr, 0,
                                          cmid, 512, 1024, 1);
  logits_kernel<<<1, 256, 0, stream>>>(cmid, Wc2, bc2, (float*)d_out);
}